// Round 3
// baseline (1033.140 us; speedup 1.0000x reference)
//
#include <hip/hip_runtime.h>
#include <stdint.h>

typedef __bf16 bf16;
typedef __bf16 bf16x8 __attribute__((ext_vector_type(8)));
typedef float f32x4 __attribute__((ext_vector_type(4)));

#define B_DIM 4096
#define HID   1024
#define KPSZ  256

#define BM  128   // m-tile (batch rows)
#define BNH 32    // n-tile within H
#define BK  64    // k-step

// ---- runtime dtype detection -------------------------------------------
// Sample low 16 bits of the first 512 dwords of kps. bf16 mode: those are
// bf16 values ~N(0,1) -> biased-exponent field in [100,140] for essentially
// all samples (count ~512/512). fp32 mode: those are random low mantissa
// bits -> that field is uniform (count ~82/512). Threshold 256 separates by
// >20 sigma. Deterministic, wave-uniform, identical for every block & call.
__device__ __forceinline__ bool detect_b16(const void* kps) {
  const uint16_t* k16 = (const uint16_t*)kps;
  int lane = threadIdx.x & 63;
  int c = 0;
#pragma unroll
  for (int j = 0; j < 8; ++j) {
    uint16_t v = k16[(lane * 8 + j) * 2];
    int e = (v >> 7) & 0xFF;
    c += (e >= 100 && e <= 140) ? 1 : 0;
  }
#pragma unroll
  for (int s = 1; s < 64; s <<= 1) c += __shfl_xor(c, s, 64);
  return c > 256;
}

// load 8 consecutive elements as bf16x8, from bf16 or fp32 storage
__device__ __forceinline__ bf16x8 load8(const void* base, size_t off, bool b16) {
  if (b16) {
    return *(const bf16x8*)((const bf16*)base + off);
  } else {
    const float* f = (const float*)base + off;
    float4 lo = *(const float4*)f;
    float4 hi = *(const float4*)(f + 4);
    bf16x8 r;
    r[0] = (bf16)lo.x; r[1] = (bf16)lo.y; r[2] = (bf16)lo.z; r[3] = (bf16)lo.w;
    r[4] = (bf16)hi.x; r[5] = (bf16)hi.y; r[6] = (bf16)hi.z; r[7] = (bf16)hi.w;
    return r;
  }
}
__device__ __forceinline__ float ldg1(const void* p, size_t i, bool b16) {
  return b16 ? (float)((const bf16*)p)[i] : ((const float*)p)[i];
}
__device__ __forceinline__ void stg1(void* p, size_t i, float v, bool b16) {
  if (b16) ((bf16*)p)[i] = (bf16)v;
  else     ((float*)p)[i] = v;
}

__device__ __forceinline__ float sigm(float x) {
  return 1.0f / (1.0f + __expf(-x));
}
__device__ __forceinline__ float tanhx(float x) {
  float e = __expf(-2.0f * fabsf(x));
  float t = (1.0f - e) / (1.0f + e);
  return x < 0.0f ? -t : t;
}

// ---------------- embedding GEMM: in_frame = kps @ W_emb^T + b_emb --------
__global__ __launch_bounds__(256)
void emb_kernel(const void* __restrict__ kps, const void* __restrict__ W,
                const void* __restrict__ bias, void* __restrict__ out) {
  __shared__ bf16 sA[BM * BK];   // 16 KB
  __shared__ bf16 sB[BNH * BK];  // 4 KB

  const bool b16 = detect_b16(kps);
  const int n0   = blockIdx.x * BNH;
  const int m0   = blockIdx.y * BM;
  const int tid  = threadIdx.x;
  const int wave = tid >> 6;
  const int lane = tid & 63;
  const int l16  = lane & 15;
  const int kg   = lane >> 4;

  f32x4 acc[2][2] = {};

  for (int k0 = 0; k0 < KPSZ; k0 += BK) {
    bf16x8 ra[4], rb;
    #pragma unroll
    for (int i = 0; i < 4; ++i) {
      int it = tid + i * 256;
      int row = it >> 3;
      int col = (it & 7) * 8;
      ra[i] = load8(kps, (size_t)(m0 + row) * KPSZ + k0 + col, b16);
    }
    {
      int row = tid >> 3;
      int col = (tid & 7) * 8;
      rb = load8(W, (size_t)(n0 + row) * KPSZ + k0 + col, b16);
    }
    __syncthreads();   // previous iteration's LDS reads complete
    #pragma unroll
    for (int i = 0; i < 4; ++i)
      *(bf16x8*)(sA + (tid + i * 256) * 8) = ra[i];
    *(bf16x8*)(sB + tid * 8) = rb;
    __syncthreads();   // LDS writes visible

    #pragma unroll
    for (int ks = 0; ks < 2; ++ks) {
      bf16x8 a[2], b[2];
      #pragma unroll
      for (int mi = 0; mi < 2; ++mi)
        a[mi] = *(const bf16x8*)(sA + (wave * 32 + mi * 16 + l16) * BK + ks * 32 + kg * 8);
      #pragma unroll
      for (int ni = 0; ni < 2; ++ni)
        b[ni] = *(const bf16x8*)(sB + (ni * 16 + l16) * BK + ks * 32 + kg * 8);
      #pragma unroll
      for (int mi = 0; mi < 2; ++mi)
        #pragma unroll
        for (int ni = 0; ni < 2; ++ni)
          acc[mi][ni] = __builtin_amdgcn_mfma_f32_16x16x32_bf16(a[mi], b[ni], acc[mi][ni], 0, 0, 0);
    }
  }

  #pragma unroll
  for (int mi = 0; mi < 2; ++mi)
    #pragma unroll
    for (int r = 0; r < 4; ++r) {
      int m = m0 + wave * 32 + mi * 16 + kg * 4 + r;
      #pragma unroll
      for (int ni = 0; ni < 2; ++ni) {
        int n = n0 + ni * 16 + l16;
        stg1(out, (size_t)m * KPSZ + n, acc[mi][ni][r] + ldg1(bias, n, b16), b16);
      }
    }
}

// ------------- fused 4-gate GEMM + LSTM epilogue, one launch per cell ------
// Output bases are d_out with ELEMENT offsets (dtype-agnostic addressing).
__global__ __launch_bounds__(256)
void lstm_cell_kernel(const void* __restrict__ Ax, const void* __restrict__ Wih, int Kx,
                      const void* __restrict__ Ah, const void* __restrict__ Whh,
                      const void* __restrict__ bih, const void* __restrict__ bhh,
                      const void* __restrict__ Cprev,
                      void* __restrict__ outbase,
                      size_t hoff, size_t h2off, size_t coff, int dup,
                      const void* __restrict__ kps) {
  __shared__ bf16 sA[BM * BK];        // 16 KB  [128][64]
  __shared__ bf16 sW[4 * BNH * BK];   // 16 KB  [gate*32 + n32][64]

  const bool b16 = detect_b16(kps);
  const int n0   = blockIdx.x * BNH;
  const int m0   = blockIdx.y * BM;
  const int tid  = threadIdx.x;
  const int wave = tid >> 6;
  const int lane = tid & 63;
  const int l16  = lane & 15;
  const int kg   = lane >> 4;

  f32x4 acc[4][2][2] = {};

  const void* Asrc = Ax;
  const void* Wsrc = Wih;
  int K = Kx;
  for (int phase = 0; phase < 2; ++phase) {
    for (int k0 = 0; k0 < K; k0 += BK) {
      bf16x8 ra[4], rw[4];
      #pragma unroll
      for (int i = 0; i < 4; ++i) {
        int it = tid + i * 256;
        int row = it >> 3;
        int col = (it & 7) * 8;
        ra[i] = load8(Asrc, (size_t)(m0 + row) * K + k0 + col, b16);
      }
      #pragma unroll
      for (int i = 0; i < 4; ++i) {
        int it = tid + i * 256;
        int rr = it >> 3;
        int col = (it & 7) * 8;
        int grow = (rr >> 5) * HID + n0 + (rr & 31);
        rw[i] = load8(Wsrc, (size_t)grow * K + k0 + col, b16);
      }
      __syncthreads();   // previous iteration's LDS reads complete
      #pragma unroll
      for (int i = 0; i < 4; ++i)
        *(bf16x8*)(sA + (tid + i * 256) * 8) = ra[i];
      #pragma unroll
      for (int i = 0; i < 4; ++i)
        *(bf16x8*)(sW + (tid + i * 256) * 8) = rw[i];
      __syncthreads();   // LDS writes visible

      #pragma unroll
      for (int ks = 0; ks < 2; ++ks) {
        bf16x8 a[2], b[4][2];
        #pragma unroll
        for (int mi = 0; mi < 2; ++mi)
          a[mi] = *(const bf16x8*)(sA + (wave * 32 + mi * 16 + l16) * BK + ks * 32 + kg * 8);
        #pragma unroll
        for (int g = 0; g < 4; ++g)
          #pragma unroll
          for (int ni = 0; ni < 2; ++ni)
            b[g][ni] = *(const bf16x8*)(sW + (g * 32 + ni * 16 + l16) * BK + ks * 32 + kg * 8);
        #pragma unroll
        for (int g = 0; g < 4; ++g)
          #pragma unroll
          for (int mi = 0; mi < 2; ++mi)
            #pragma unroll
            for (int ni = 0; ni < 2; ++ni)
              acc[g][mi][ni] = __builtin_amdgcn_mfma_f32_16x16x32_bf16(
                  a[mi], b[g][ni], acc[g][mi][ni], 0, 0, 0);
      }
    }
    Asrc = Ah; Wsrc = Whh; K = HID;
  }

  // ---- epilogue: per-lane LSTM cell update --------------------------------
  float bsum[4][2];
  #pragma unroll
  for (int g = 0; g < 4; ++g)
    #pragma unroll
    for (int ni = 0; ni < 2; ++ni) {
      int n = n0 + ni * 16 + l16;
      bsum[g][ni] = ldg1(bih, g * HID + n, b16) + ldg1(bhh, g * HID + n, b16);
    }

  #pragma unroll
  for (int mi = 0; mi < 2; ++mi)
    #pragma unroll
    for (int r = 0; r < 4; ++r) {
      int m = m0 + wave * 32 + mi * 16 + kg * 4 + r;
      size_t rowoff = (size_t)m * HID;
      #pragma unroll
      for (int ni = 0; ni < 2; ++ni) {
        int n = n0 + ni * 16 + l16;
        float xi = acc[0][mi][ni][r] + bsum[0][ni];
        float xf = acc[1][mi][ni][r] + bsum[1][ni];
        float xg = acc[2][mi][ni][r] + bsum[2][ni];
        float xo = acc[3][mi][ni][r] + bsum[3][ni];
        float I = sigm(xi);
        float F = sigm(xf);
        float G = tanhx(xg);
        float O = sigm(xo);
        float c  = ldg1(Cprev, rowoff + n, b16);
        float cn = F * c + I * G;
        float hn = O * tanhx(cn);
        stg1(outbase, coff + rowoff + n, cn, b16);
        stg1(outbase, hoff + rowoff + n, hn, b16);
        if (dup) stg1(outbase, h2off + rowoff + n, hn, b16);
      }
    }
}

extern "C" void kernel_launch(void* const* d_in, const int* in_sizes, int n_in,
                              void* d_out, int out_size, void* d_ws, size_t ws_size,
                              hipStream_t stream) {
  const void* kps   = d_in[0];
  const void* h0    = d_in[1];
  const void* h1    = d_in[2];
  const void* h2    = d_in[3];
  const void* c0    = d_in[4];
  const void* c1    = d_in[5];
  const void* c2    = d_in[6];
  const void* W_emb = d_in[7];
  const void* b_emb = d_in[8];
  const void* w_ih1 = d_in[9];
  const void* w_hh1 = d_in[10];
  const void* b_ih1 = d_in[11];
  const void* b_hh1 = d_in[12];
  const void* w_ih2 = d_in[13];
  const void* w_hh2 = d_in[14];
  const void* b_ih2 = d_in[15];
  const void* b_hh2 = d_in[16];
  const void* w_ih3 = d_in[17];
  const void* w_hh3 = d_in[18];
  const void* b_ih3 = d_in[19];
  const void* b_hh3 = d_in[20];

  void* in_frame = d_ws;   // [4096 x 256] in detected dtype (<= 4 MB)
  const size_t S = (size_t)B_DIM * HID;

  // out chunks (element offsets): 0:h2n 1:h0n 2:h1n 3:h2n 4:c0n 5:c1n 6:c2n
  emb_kernel<<<dim3(KPSZ / BNH, B_DIM / BM), 256, 0, stream>>>(kps, W_emb, b_emb, in_frame);

  dim3 grid(HID / BNH, B_DIM / BM);
  // cell 1: x=in_frame (K=256), h=h0 -> h0n(c1), c0n(c4)
  lstm_cell_kernel<<<grid, 256, 0, stream>>>(in_frame, w_ih1, KPSZ, h0, w_hh1,
                                             b_ih1, b_hh1, c0,
                                             d_out, 1 * S, 0, 4 * S, 0, kps);
  // cell 2: x=h0 (old), h=h1 -> h1n(c2), c1n(c5)
  lstm_cell_kernel<<<grid, 256, 0, stream>>>(h0, w_ih2, HID, h1, w_hh2,
                                             b_ih2, b_hh2, c1,
                                             d_out, 2 * S, 0, 5 * S, 0, kps);
  // cell 3: x=h1 (old), h=h2 -> h2n(c0 and c3), c2n(c6)
  lstm_cell_kernel<<<grid, 256, 0, stream>>>(h1, w_ih3, HID, h2, w_hh3,
                                             b_ih3, b_hh3, c2,
                                             d_out, 0 * S, 3 * S, 6 * S, 1, kps);
}

// Round 4
// 811.704 us; speedup vs baseline: 1.2728x; 1.2728x over previous
//
#include <hip/hip_runtime.h>
#include <stdint.h>

typedef __bf16 bf16;
typedef __bf16 bf16x8 __attribute__((ext_vector_type(8)));
typedef float f32x4 __attribute__((ext_vector_type(4)));

#define B_DIM 4096
#define HID   1024
#define KPSZ  256

#define BM  128   // m-tile (batch rows)
#define BNH 32    // n-tile within H (x4 gates = 128 weight rows staged)
#define BK  64    // k-step

// ---- runtime dtype detection (unchanged from passing round) --------------
__device__ __forceinline__ bool detect_b16(const void* kps) {
  const uint16_t* k16 = (const uint16_t*)kps;
  int lane = threadIdx.x & 63;
  int c = 0;
#pragma unroll
  for (int j = 0; j < 8; ++j) {
    uint16_t v = k16[(lane * 8 + j) * 2];
    int e = (v >> 7) & 0xFF;
    c += (e >= 100 && e <= 140) ? 1 : 0;
  }
#pragma unroll
  for (int s = 1; s < 64; s <<= 1) c += __shfl_xor(c, s, 64);
  return c > 256;
}

__device__ __forceinline__ bf16x8 load8(const void* base, size_t off, bool b16) {
  if (b16) {
    return *(const bf16x8*)((const bf16*)base + off);
  } else {
    const float* f = (const float*)base + off;
    float4 lo = *(const float4*)f;
    float4 hi = *(const float4*)(f + 4);
    bf16x8 r;
    r[0] = (bf16)lo.x; r[1] = (bf16)lo.y; r[2] = (bf16)lo.z; r[3] = (bf16)lo.w;
    r[4] = (bf16)hi.x; r[5] = (bf16)hi.y; r[6] = (bf16)hi.z; r[7] = (bf16)hi.w;
    return r;
  }
}
__device__ __forceinline__ float ldg1(const void* p, size_t i, bool b16) {
  return b16 ? (float)((const bf16*)p)[i] : ((const float*)p)[i];
}
__device__ __forceinline__ void stg1(void* p, size_t i, float v, bool b16) {
  if (b16) ((bf16*)p)[i] = (bf16)v;
  else     ((float*)p)[i] = v;
}

__device__ __forceinline__ float sigm(float x) {
  return 1.0f / (1.0f + __expf(-x));
}
__device__ __forceinline__ float tanhx(float x) {
  float e = __expf(-2.0f * fabsf(x));
  float t = (1.0f - e) / (1.0f + e);
  return x < 0.0f ? -t : t;
}

// XOR-swizzled LDS index: row stride 64 elems (128 B) hits all-same-bank at
// 16-way without this. Swizzle col (8-elem granular) by row&7 -> reads and
// writes become <=2-way (free, m136). Preserves 16 B alignment for b128.
__device__ __forceinline__ int sw(int row, int col8) {
  return row * BK + (col8 ^ ((row & 7) << 3));
}

// ---------------- embedding GEMM: in_frame = kps @ W_emb^T + b_emb --------
__global__ __launch_bounds__(256)
void emb_kernel(const void* __restrict__ kps, const void* __restrict__ W,
                const void* __restrict__ bias, void* __restrict__ out) {
  __shared__ bf16 sA[BM * BK];   // 16 KB
  __shared__ bf16 sB[BNH * BK];  // 4 KB

  const bool b16 = detect_b16(kps);
  const int n0   = blockIdx.x * BNH;
  const int m0   = blockIdx.y * BM;
  const int tid  = threadIdx.x;
  const int wave = tid >> 6;
  const int lane = tid & 63;
  const int l16  = lane & 15;
  const int kg   = lane >> 4;

  f32x4 acc[2][2] = {};

  bf16x8 ra[4], rb;
  // prefetch step 0
  #pragma unroll
  for (int i = 0; i < 4; ++i) {
    int it = tid + i * 256;
    ra[i] = load8(kps, (size_t)(m0 + (it >> 3)) * KPSZ + (it & 7) * 8, b16);
  }
  rb = load8(W, (size_t)(n0 + (tid >> 3)) * KPSZ + (tid & 7) * 8, b16);

  for (int s = 0; s < KPSZ / BK; ++s) {
    __syncthreads();   // previous iteration's LDS reads complete
    #pragma unroll
    for (int i = 0; i < 4; ++i) {
      int it = tid + i * 256;
      *(bf16x8*)(sA + sw(it >> 3, (it & 7) * 8)) = ra[i];
    }
    *(bf16x8*)(sB + sw(tid >> 3, (tid & 7) * 8)) = rb;
    __syncthreads();   // LDS writes visible

    if (s + 1 < KPSZ / BK) {
      int k0 = (s + 1) * BK;
      #pragma unroll
      for (int i = 0; i < 4; ++i) {
        int it = tid + i * 256;
        ra[i] = load8(kps, (size_t)(m0 + (it >> 3)) * KPSZ + k0 + (it & 7) * 8, b16);
      }
      rb = load8(W, (size_t)(n0 + (tid >> 3)) * KPSZ + k0 + (tid & 7) * 8, b16);
    }

    #pragma unroll
    for (int ks = 0; ks < 2; ++ks) {
      bf16x8 a[2], b[2];
      #pragma unroll
      for (int mi = 0; mi < 2; ++mi) {
        int row = wave * 32 + mi * 16 + l16;
        a[mi] = *(const bf16x8*)(sA + sw(row, ks * 32 + kg * 8));
      }
      #pragma unroll
      for (int ni = 0; ni < 2; ++ni) {
        int row = ni * 16 + l16;
        b[ni] = *(const bf16x8*)(sB + sw(row, ks * 32 + kg * 8));
      }
      #pragma unroll
      for (int mi = 0; mi < 2; ++mi)
        #pragma unroll
        for (int ni = 0; ni < 2; ++ni)
          acc[mi][ni] = __builtin_amdgcn_mfma_f32_16x16x32_bf16(a[mi], b[ni], acc[mi][ni], 0, 0, 0);
    }
  }

  #pragma unroll
  for (int mi = 0; mi < 2; ++mi)
    #pragma unroll
    for (int r = 0; r < 4; ++r) {
      int m = m0 + wave * 32 + mi * 16 + kg * 4 + r;
      #pragma unroll
      for (int ni = 0; ni < 2; ++ni) {
        int n = n0 + ni * 16 + l16;
        stg1(out, (size_t)m * KPSZ + n, acc[mi][ni][r] + ldg1(bias, n, b16), b16);
      }
    }
}

// ------------- fused 4-gate GEMM + LSTM epilogue, 3 cells via blockIdx.z ---
struct CellArgs {
  const void *Ax, *Wih, *Ah, *Whh, *bih, *bhh, *Cprev;
  size_t hoff, h2off, coff;
  int Kx, dup;
};
struct Args3 {
  CellArgs c[3];
  void* outbase;
  const void* kps;
};

__global__ __launch_bounds__(256)
void lstm_cells_kernel(Args3 A) {
  __shared__ bf16 sA[BM * BK];        // 16 KB  [128][64] swizzled
  __shared__ bf16 sW[4 * BNH * BK];   // 16 KB  [gate*32 + n32][64] swizzled

  const CellArgs p = A.c[blockIdx.z];
  const bool b16 = detect_b16(A.kps);
  const int n0   = blockIdx.x * BNH;
  const int m0   = blockIdx.y * BM;
  const int tid  = threadIdx.x;
  const int wave = tid >> 6;
  const int lane = tid & 63;
  const int l16  = lane & 15;
  const int kg   = lane >> 4;

  f32x4 acc[4][2][2] = {};

  const int steps1 = p.Kx / BK;
  const int steps  = steps1 + HID / BK;

  bf16x8 ra[4], rw[4];
  // prefetch step 0 (always phase-0: Ax/Wih)
  #pragma unroll
  for (int i = 0; i < 4; ++i) {
    int it = tid + i * 256;
    ra[i] = load8(p.Ax, (size_t)(m0 + (it >> 3)) * p.Kx + (it & 7) * 8, b16);
  }
  #pragma unroll
  for (int i = 0; i < 4; ++i) {
    int it = tid + i * 256;
    int rr = it >> 3;
    int grow = (rr >> 5) * HID + n0 + (rr & 31);
    rw[i] = load8(p.Wih, (size_t)grow * p.Kx + (it & 7) * 8, b16);
  }

  for (int s = 0; s < steps; ++s) {
    __syncthreads();   // previous iteration's LDS reads complete
    #pragma unroll
    for (int i = 0; i < 4; ++i) {
      int it = tid + i * 256;
      *(bf16x8*)(sA + sw(it >> 3, (it & 7) * 8)) = ra[i];
    }
    #pragma unroll
    for (int i = 0; i < 4; ++i) {
      int it = tid + i * 256;
      *(bf16x8*)(sW + sw(it >> 3, (it & 7) * 8)) = rw[i];
    }
    __syncthreads();   // LDS writes visible

    // prefetch step s+1 while MFMAs below run (overlaps HBM/L2 latency)
    if (s + 1 < steps) {
      const void *A_, *W_; int K_, k0_;
      int s2 = s + 1;
      if (s2 < steps1) { A_ = p.Ax; W_ = p.Wih; K_ = p.Kx; k0_ = s2 * BK; }
      else             { A_ = p.Ah; W_ = p.Whh; K_ = HID;  k0_ = (s2 - steps1) * BK; }
      #pragma unroll
      for (int i = 0; i < 4; ++i) {
        int it = tid + i * 256;
        ra[i] = load8(A_, (size_t)(m0 + (it >> 3)) * K_ + k0_ + (it & 7) * 8, b16);
      }
      #pragma unroll
      for (int i = 0; i < 4; ++i) {
        int it = tid + i * 256;
        int rr = it >> 3;
        int grow = (rr >> 5) * HID + n0 + (rr & 31);
        rw[i] = load8(W_, (size_t)grow * K_ + k0_ + (it & 7) * 8, b16);
      }
    }

    #pragma unroll
    for (int ks = 0; ks < 2; ++ks) {
      bf16x8 a[2], b[4][2];
      #pragma unroll
      for (int mi = 0; mi < 2; ++mi) {
        int row = wave * 32 + mi * 16 + l16;
        a[mi] = *(const bf16x8*)(sA + sw(row, ks * 32 + kg * 8));
      }
      #pragma unroll
      for (int g = 0; g < 4; ++g)
        #pragma unroll
        for (int ni = 0; ni < 2; ++ni) {
          int row = g * 32 + ni * 16 + l16;
          b[g][ni] = *(const bf16x8*)(sW + sw(row, ks * 32 + kg * 8));
        }
      #pragma unroll
      for (int g = 0; g < 4; ++g)
        #pragma unroll
        for (int mi = 0; mi < 2; ++mi)
          #pragma unroll
          for (int ni = 0; ni < 2; ++ni)
            acc[g][mi][ni] = __builtin_amdgcn_mfma_f32_16x16x32_bf16(
                a[mi], b[g][ni], acc[g][mi][ni], 0, 0, 0);
    }
  }

  // ---- epilogue: per-lane LSTM cell update --------------------------------
  float bsum[4][2];
  #pragma unroll
  for (int g = 0; g < 4; ++g)
    #pragma unroll
    for (int ni = 0; ni < 2; ++ni) {
      int n = n0 + ni * 16 + l16;
      bsum[g][ni] = ldg1(p.bih, g * HID + n, b16) + ldg1(p.bhh, g * HID + n, b16);
    }

  #pragma unroll
  for (int mi = 0; mi < 2; ++mi)
    #pragma unroll
    for (int r = 0; r < 4; ++r) {
      int m = m0 + wave * 32 + mi * 16 + kg * 4 + r;
      size_t rowoff = (size_t)m * HID;
      #pragma unroll
      for (int ni = 0; ni < 2; ++ni) {
        int n = n0 + ni * 16 + l16;
        float xi = acc[0][mi][ni][r] + bsum[0][ni];
        float xf = acc[1][mi][ni][r] + bsum[1][ni];
        float xg = acc[2][mi][ni][r] + bsum[2][ni];
        float xo = acc[3][mi][ni][r] + bsum[3][ni];
        float I = sigm(xi);
        float F = sigm(xf);
        float G = tanhx(xg);
        float O = sigm(xo);
        float c  = ldg1(p.Cprev, rowoff + n, b16);
        float cn = F * c + I * G;
        float hn = O * tanhx(cn);
        stg1(A.outbase, p.coff + rowoff + n, cn, b16);
        stg1(A.outbase, p.hoff + rowoff + n, hn, b16);
        if (p.dup) stg1(A.outbase, p.h2off + rowoff + n, hn, b16);
      }
    }
}

extern "C" void kernel_launch(void* const* d_in, const int* in_sizes, int n_in,
                              void* d_out, int out_size, void* d_ws, size_t ws_size,
                              hipStream_t stream) {
  const void* kps   = d_in[0];
  const void* h0    = d_in[1];
  const void* h1    = d_in[2];
  const void* h2    = d_in[3];
  const void* c0    = d_in[4];
  const void* c1    = d_in[5];
  const void* c2    = d_in[6];
  const void* W_emb = d_in[7];
  const void* b_emb = d_in[8];
  const void* w_ih1 = d_in[9];
  const void* w_hh1 = d_in[10];
  const void* b_ih1 = d_in[11];
  const void* b_hh1 = d_in[12];
  const void* w_ih2 = d_in[13];
  const void* w_hh2 = d_in[14];
  const void* b_ih2 = d_in[15];
  const void* b_hh2 = d_in[16];
  const void* w_ih3 = d_in[17];
  const void* w_hh3 = d_in[18];
  const void* b_ih3 = d_in[19];
  const void* b_hh3 = d_in[20];

  void* in_frame = d_ws;   // [4096 x 256] in detected dtype (<= 4 MB)
  const size_t S = (size_t)B_DIM * HID;

  // out chunks (element offsets): 0:h2n 1:h0n 2:h1n 3:h2n 4:c0n 5:c1n 6:c2n
  emb_kernel<<<dim3(KPSZ / BNH, B_DIM / BM), 256, 0, stream>>>(kps, W_emb, b_emb, in_frame);

  Args3 A;
  A.outbase = d_out;
  A.kps = kps;
  A.c[0] = { in_frame, w_ih1, h0, w_hh1, b_ih1, b_hh1, c0,
             1 * S, 0, 4 * S, KPSZ, 0 };
  A.c[1] = { h0, w_ih2, h1, w_hh2, b_ih2, b_hh2, c1,
             2 * S, 0, 5 * S, HID, 0 };
  A.c[2] = { h1, w_ih3, h2, w_hh3, b_ih3, b_hh3, c2,
             0 * S, 3 * S, 6 * S, HID, 1 };

  lstm_cells_kernel<<<dim3(HID / BNH, B_DIM / BM, 3), 256, 0, stream>>>(A);
}